// Round 13
// baseline (382.450 us; speedup 1.0000x reference)
//
#include <hip/hip_runtime.h>
#include <type_traits>

#define N 4096

// ======== border iterative kernel (round-11 proven structure, 32 steps) ========
#define BT 64              // border output tile
#define BH 32              // halo = steps
#define SD 128             // staged dim
#define NSTRIP 16
#define GH 8
#define BSTEPS 32
#define NBT 64             // 4096/64 grid
#define SPAD 132

// ======== separable diagonal pass ========
#define B 32               // diag tile
#define SST 68             // skew LDS row stride (68%32=4 -> bank de-phase, %4=0 -> b128 ok)
#define OST 36             // out-tile stride
#define SGUARD 64

// C(32,k) — binomial weights of (S+S^-1)^32; sum = 2^32 per pass.
__device__ constexpr float BIN32[33] = {
    1.f, 32.f, 496.f, 4960.f, 35960.f, 201376.f, 906192.f, 3365856.f,
    10518300.f, 28048800.f, 64512240.f, 129024480.f, 225792840.f,
    347373600.f, 471435600.f, 565722720.f, 601080390.f, 565722720.f,
    471435600.f, 347373600.f, 225792840.f, 129024480.f, 64512240.f,
    28048800.f, 10518300.f, 3365856.f, 906192.f, 201376.f, 35960.f,
    4960.f, 496.f, 32.f, 1.f};

// DPP lane shifts within 16-lane rows (verified round 11).
__device__ __forceinline__ float dpp_prev(float x) {   // lane i <- lane i-1 (row_shr:1)
    int r = __builtin_amdgcn_update_dpp(__float_as_int(x), __float_as_int(x),
                                        0x111, 0xf, 0xf, false);
    return __int_as_float(r);
}
__device__ __forceinline__ float dpp_next(float x) {   // lane i <- lane i+1 (row_shl:1)
    int r = __builtin_amdgcn_update_dpp(__float_as_int(x), __float_as_int(x),
                                        0x101, 0xf, 0xf, false);
    return __int_as_float(r);
}

// Diffuse/AO shading for 4 pixels (rx carries 2^64 deferred scale).
__device__ __forceinline__ float4 shade(float4 v, float4 h, float4 n0, float4 n1, float4 n2) {
    const float SC = 0x1p-64f;
    const float L0 = 0.7053f, L1 = -0.7053f, L2 = 0.7053f;
    float4 o;
    {
        float ao = 1.0f - fminf(fmaxf((v.x * SC - h.x) * 4.0f, 0.0f), 1.0f);
        float d1 = fmaxf(n0.x * L0 + n1.x * L1 + n2.x * L2, 0.0f);
        o.x = (d1 * 0.3f + 0.7f) * ao;
    }
    {
        float ao = 1.0f - fminf(fmaxf((v.y * SC - h.y) * 4.0f, 0.0f), 1.0f);
        float d1 = fmaxf(n0.y * L0 + n1.y * L1 + n2.y * L2, 0.0f);
        o.y = (d1 * 0.3f + 0.7f) * ao;
    }
    {
        float ao = 1.0f - fminf(fmaxf((v.z * SC - h.z) * 4.0f, 0.0f), 1.0f);
        float d1 = fmaxf(n0.z * L0 + n1.z * L1 + n2.z * L2, 0.0f);
        o.z = (d1 * 0.3f + 0.7f) * ao;
    }
    {
        float ao = 1.0f - fminf(fmaxf((v.w * SC - h.w) * 4.0f, 0.0f), 1.0f);
        float d1 = fmaxf(n0.w * L0 + n1.w * L1 + n2.w * L2, 0.0f);
        o.w = (d1 * 0.3f + 0.7f) * ao;
    }
    return o;
}

// ---------------- 32-step iterative border kernel (frame tiles only) ----------------
// Covers [0,4096)^2 \ [64,4032)^2 exactly (frame of 64-wide tiles). Fused shade.
__global__ __launch_bounds__(256, 2) void border32(const float* __restrict__ src,
                                                   float* __restrict__ dst,
                                                   const float* __restrict__ xin,
                                                   const float* __restrict__ nrm) {
    const int bx = blockIdx.x, by = blockIdx.y;
    if (!(bx == 0 || by == 0 || bx == NBT - 1 || by == NBT - 1)) return;
    __shared__ float bnd[2][2][NSTRIP][SPAD];
    const int gi0 = by * BT - BH;
    const int gj0 = bx * BT - BH;
    const int tid = (int)threadIdx.x;
    const int g   = tid >> 4;          // strip 0..15
    const int l   = tid & 15;          // 8-col lane
    const int jc  = 8 * l;
    const int r0  = 8 * g;

    float4 ra[GH], rb[GH];
    auto ld4 = [&](int r, int c0) -> float4 {
        int gr = gi0 + r;
        gr = gr < 0 ? 0 : (gr > N - 1 ? N - 1 : gr);
        const int gc = gj0 + c0;
        if (gc >= 0 && gc + 3 <= N - 1)
            return *(const float4*)(src + (size_t)gr * N + gc);
        const float* row = src + (size_t)gr * N;
        return make_float4(row[min(max(gc + 0, 0), N - 1)],
                           row[min(max(gc + 1, 0), N - 1)],
                           row[min(max(gc + 2, 0), N - 1)],
                           row[min(max(gc + 3, 0), N - 1)]);
    };
#pragma unroll
    for (int k = 0; k < GH; ++k) {
        ra[k] = ld4(r0 + k, jc);
        rb[k] = ld4(r0 + k, jc + 4);
    }
    const int gc0 = gj0 + jc;
    const bool lcl = (gc0 == 0);
    const bool rcl = (gc0 + 7 == N - 1);

    *(float4*)&bnd[0][0][g][jc]     = ra[0];
    *(float4*)&bnd[0][0][g][jc + 4] = rb[0];
    *(float4*)&bnd[0][1][g][jc]     = ra[GH - 1];
    *(float4*)&bnd[0][1][g][jc + 4] = rb[GH - 1];
    __syncthreads();

    const int gm = (g == 0) ? 0 : g - 1;
    const int gp = (g == NSTRIP - 1) ? NSTRIP - 1 : g + 1;

#pragma unroll 1
    for (int p = 0; p < BSTEPS; ++p) {
        const int s = p + 1;
        const int cbuf = p & 1;
        float4 ua = *(const float4*)&bnd[cbuf][1][gm][jc];
        float4 ub = *(const float4*)&bnd[cbuf][1][gm][jc + 4];
        float4 da = *(const float4*)&bnd[cbuf][0][gp][jc];
        float4 db = *(const float4*)&bnd[cbuf][0][gp][jc + 4];
        float4 pa = ua, pb = ub;
#pragma unroll
        for (int k = 0; k < GH; ++k) {
            const int r = r0 + k;
            const float4 ca = ra[k], cb = rb[k];
            const float4 na  = (k < GH - 1) ? ra[k + 1] : da;
            const float4 nb2 = (k < GH - 1) ? rb[k + 1] : db;
            if (r >= s && r < SD - s) {
                float lft = dpp_prev(cb.w);
                float rgt = dpp_next(ca.x);
                float4 upa = pa, upb = pb, dna = na, dnb = nb2;
                const int gr = gi0 + r;
                if (gr == 0)     { upa = ca; upb = cb; }
                if (gr == N - 1) { dna = ca; dnb = cb; }
                if (lcl) lft = ca.x;
                if (rcl) rgt = cb.w;
                float4 oa, ob;
                oa.x = (upa.x + dna.x) + (lft  + ca.y);
                oa.y = (upa.y + dna.y) + (ca.x + ca.z);
                oa.z = (upa.z + dna.z) + (ca.y + ca.w);
                oa.w = (upa.w + dna.w) + (ca.z + cb.x);
                ob.x = (upb.x + dnb.x) + (ca.w + cb.y);
                ob.y = (upb.y + dnb.y) + (cb.x + cb.z);
                ob.z = (upb.z + dnb.z) + (cb.y + cb.w);
                ob.w = (upb.w + dnb.w) + (cb.z + rgt);
                ra[k] = oa; rb[k] = ob;
            }
            pa = ca; pb = cb;
        }
        const int nbuf = cbuf ^ 1;
        *(float4*)&bnd[nbuf][0][g][jc]     = ra[0];
        *(float4*)&bnd[nbuf][0][g][jc + 4] = rb[0];
        *(float4*)&bnd[nbuf][1][g][jc]     = ra[GH - 1];
        *(float4*)&bnd[nbuf][1][g][jc + 4] = rb[GH - 1];
        __syncthreads();
    }

    // store interior [BH, SD-BH) = tile area, fused shade
    if (l >= BH / 8 && l < (SD - BH) / 8) {
#pragma unroll
        for (int k = 0; k < GH; ++k) {
            const int r = r0 + k;
            if (r < BH || r >= SD - BH) continue;
            const int gr = gi0 + r;
            if (gr < 0 || gr >= N) continue;
            if (gc0 < 0 || gc0 + 7 >= N + 0) { }   // cols always in-bounds for stored l-range
            const size_t base = (size_t)gr * N + gc0;
            {
                const float4 h  = *(const float4*)(xin + base);
                const float4 n0 = *(const float4*)(nrm + base);
                const float4 n1 = *(const float4*)(nrm + (size_t)N * N + base);
                const float4 n2 = *(const float4*)(nrm + 2 * (size_t)N * N + base);
                *(float4*)(dst + base) = shade(ra[k], h, n0, n1, n2);
            }
            {
                const float4 h  = *(const float4*)(xin + base + 4);
                const float4 n0 = *(const float4*)(nrm + base + 4);
                const float4 n1 = *(const float4*)(nrm + (size_t)N * N + base + 4);
                const float4 n2 = *(const float4*)(nrm + 2 * (size_t)N * N + base + 4);
                *(float4*)(dst + base + 4) = shade(rb[k], h, n0, n1, n2);
            }
        }
    }
}

// ---------------- separable diagonal 33-tap pass, skewed LDS ----------------
// DIR=0 (P1): t(x,y)=Σ C32[k] f(x+k-16, y-(k-16)); skew row = lx'+ly' (keep rows 32..94 -> r=row-32)
// DIR=1 (P2): out  =Σ C32[k] t(x+k-16, y+(k-16));  skew row = lx'-ly'+63
// In skewed space: output diag d -> LDS row d, taps at cols lx..lx+32 (contiguous).
// Tile offsets chosen so staging is ALWAYS in-bounds (no clamps).
template <int DIR, int FUSE>
__global__ __launch_bounds__(256, 4) void diagpass(const float* __restrict__ src,
                                                   float* __restrict__ dst,
                                                   const float* __restrict__ xin,
                                                   const float* __restrict__ nrm,
                                                   int toff) {
    __shared__ float S[63 * SST + SGUARD];   // skew rows 0..62 (+guard)
    __shared__ float S2[B * OST];            // out tile, row-major
    const int X0 = (blockIdx.x + toff) * B;
    const int Y0 = (blockIdx.y + toff) * B;
    const int tid = (int)threadIdx.x;

    // ---- stage 64x64 rect, skew-scatter (4 scalar LDS writes per float4) ----
    for (int m = tid; m < 64 * 16; m += 256) {
        const int ly  = m >> 4;          // 0..63
        const int lx4 = m & 15;          // 0..15
        const int lyp = ly - 16;         // -16..47
        const int lxp = 4 * lx4 - 16;    // -16..44 (.x)
        const float4 v = *(const float4*)(src + (size_t)(Y0 + lyp) * N + (X0 + lxp));
        const int row0 = (DIR == 0) ? (lxp + lyp + 32) : (lxp - lyp + 63);
        const int col0 = lxp + 16;       // 0..60
        const int r0 = row0 - 32;        // keep rows [32,94] -> r in [0,62]
#pragma unroll
        for (int e = 0; e < 4; ++e) {
            const int r = r0 + e;
            const float val = (e == 0) ? v.x : (e == 1) ? v.y : (e == 2) ? v.z : v.w;
            if (r >= 0 && r <= 62) S[r * SST + col0 + e] = val;
        }
    }
    __syncthreads();

    // ---- conv: thread (d = tid>>2, h = tid&3) computes 8 outputs on diag d ----
    const int d  = tid >> 2;             // 0..63 (63 invalid)
    const int h  = tid & 3;
    const int lo = max(0, d - 31);
    const int hi = min(31, d);
    const int L  = (lo & ~3) + 8 * h;
    const bool active = (d <= 62) && (L <= hi);
    float acc[8];
    if (active) {
        const int rowBase = d * SST;
        float w[40];
#pragma unroll
        for (int j = 0; j < 10; ++j)
            *(float4*)&w[4 * j] = *(const float4*)&S[rowBase + L + 4 * j];
#pragma unroll
        for (int i = 0; i < 8; ++i) acc[i] = 0.f;
#pragma unroll
        for (int k = 0; k <= 32; ++k) {
            const float c = BIN32[k];
#pragma unroll
            for (int i = 0; i < 8; ++i) acc[i] = fmaf(c, w[i + k], acc[i]);
        }
        // scatter valid outputs into row-major out tile
#pragma unroll
        for (int i = 0; i < 8; ++i) {
            const int lx = L + i;
            if (lx >= lo && lx <= hi) {
                const int ly = (DIR == 0) ? (d - lx) : (lx - d + 31);
                S2[ly * OST + lx] = acc[i];
            }
        }
    }
    __syncthreads();

    // ---- coalesced writeback (1 float4 per thread) ----
    {
        const int ly  = tid >> 3;        // 0..31
        const int lx4 = tid & 7;         // 0..7
        const float4 v = *(const float4*)&S2[ly * OST + 4 * lx4];
        const size_t base = (size_t)(Y0 + ly) * N + X0 + 4 * lx4;
        if constexpr (FUSE) {
            const float4 h4 = *(const float4*)(xin + base);
            const float4 n0 = *(const float4*)(nrm + base);
            const float4 n1 = *(const float4*)(nrm + (size_t)N * N + base);
            const float4 n2 = *(const float4*)(nrm + 2 * (size_t)N * N + base);
            *(float4*)(dst + base) = shade(v, h4, n0, n1, n2);
        } else {
            *(float4*)(dst + base) = v;
        }
    }
}

extern "C" void kernel_launch(void* const* d_in, const int* in_sizes, int n_in,
                              void* d_out, int out_size, void* d_ws, size_t ws_size,
                              hipStream_t stream) {
    const float* x       = (const float*)d_in[0];
    const float* normals = (const float*)d_in[1];
    float* out = (float*)d_out;
    float* ws  = (float*)d_ws;

    dim3 block(256);

    // P1: anti-diag binomial, tiles [1,126]^2 (staging in-bounds; produces t on [32,4064)^2,
    //     valid wherever taps are in-bounds — covers all P2 reads [48,4048)^2). x -> ws.
    dim3 g1(126, 126);
    diagpass<0, 0><<<g1, block, 0, stream>>>(x, ws, nullptr, nullptr, 1);

    // P2: main-diag binomial + fused shade, tiles [2,125]^2 -> stores [64,4032)^2. ws -> out.
    dim3 g2(124, 124);
    diagpass<1, 1><<<g2, block, 0, stream>>>(ws, out, x, normals, 2);

    // Border frame [0,4096)^2 \ [64,4032)^2: exact 32-step iterative, fused shade. x -> out.
    dim3 g3(NBT, NBT);
    border32<<<g3, block, 0, stream>>>(x, out, x, normals);
}

// Round 14
// 155.587 us; speedup vs baseline: 2.4581x; 2.4581x over previous
//
#include <hip/hip_runtime.h>

#define N 4096
#define B 32
#define SST 68     // skew LDS row stride (68%32=4 -> bank de-phase, %4=0 -> b128 ok)
#define OST 36     // out-tile stride
#define SGUARD 64

// C(32,k) — binomial weights of (S+S^-1)^32; sum = 2^32 per pass.
__device__ constexpr float BIN32[33] = {
    1.f, 32.f, 496.f, 4960.f, 35960.f, 201376.f, 906192.f, 3365856.f,
    10518300.f, 28048800.f, 64512240.f, 129024480.f, 225792840.f,
    347373600.f, 471435600.f, 565722720.f, 601080390.f, 565722720.f,
    471435600.f, 347373600.f, 225792840.f, 129024480.f, 64512240.f,
    28048800.f, 10518300.f, 3365856.f, 906192.f, 201376.f, 35960.f,
    4960.f, 496.f, 32.f, 1.f};

// Half-sample mirror (replicate-pad iteration == free-space on this extension).
__device__ __forceinline__ int mir(int c) {
    c = (c < 0) ? (-1 - c) : c;
    return (c >= N) ? (2 * N - 1 - c) : c;
}

// Extended-t strips (tx>=4080 or ty>=4080) live in d_out at rows 64..128, cols <4064
// (disjoint from every P2-edge write, overwritten by P2-interior afterwards).
__device__ __forceinline__ size_t strip_off(int tx, int ty) {
    long e = (tx >= 4080) ? ((long)(ty + 16) * 32 + (tx - 4080))            // R1: 32x4128
                          : (132096L + (long)(ty - 4080) * (long)N + (tx + 16)); // R2: 4096x32
    return (size_t)(64 + e / 4064) * N + (size_t)(e % 4064);
}

// Diffuse/AO shading for 4 pixels (rx carries 2^64 deferred scale).
__device__ __forceinline__ float4 shade(float4 v, float4 h, float4 n0, float4 n1, float4 n2) {
    const float SC = 0x1p-64f;
    const float L0 = 0.7053f, L1 = -0.7053f, L2 = 0.7053f;
    float4 o;
    {
        float ao = 1.0f - fminf(fmaxf((v.x * SC - h.x) * 4.0f, 0.0f), 1.0f);
        float d1 = fmaxf(n0.x * L0 + n1.x * L1 + n2.x * L2, 0.0f);
        o.x = (d1 * 0.3f + 0.7f) * ao;
    }
    {
        float ao = 1.0f - fminf(fmaxf((v.y * SC - h.y) * 4.0f, 0.0f), 1.0f);
        float d1 = fmaxf(n0.y * L0 + n1.y * L1 + n2.y * L2, 0.0f);
        o.y = (d1 * 0.3f + 0.7f) * ao;
    }
    {
        float ao = 1.0f - fminf(fmaxf((v.z * SC - h.z) * 4.0f, 0.0f), 1.0f);
        float d1 = fmaxf(n0.z * L0 + n1.z * L1 + n2.z * L2, 0.0f);
        o.z = (d1 * 0.3f + 0.7f) * ao;
    }
    {
        float ao = 1.0f - fminf(fmaxf((v.w * SC - h.w) * 4.0f, 0.0f), 1.0f);
        float d1 = fmaxf(n0.w * L0 + n1.w * L1 + n2.w * L2, 0.0f);
        o.w = (d1 * 0.3f + 0.7f) * ao;
    }
    return o;
}

// ---------------- P1: anti-diagonal 33-tap pass over extended grid ----------------
// Grid 129x129; tile covers t on [32bx-16, 32bx+16) x [32by-16, 32by+16).
// Mirror staging at the 516 edge tiles; core t -> ws (+16 shift), strips -> d_out R.
__global__ __launch_bounds__(256, 4) void p1_antidiag(const float* __restrict__ src,
                                                      float* __restrict__ tcore,
                                                      float* __restrict__ tstrip) {
    __shared__ float S[63 * SST + SGUARD];
    __shared__ float S2[B * OST];
    const int bx = blockIdx.x, by = blockIdx.y;
    const int X0 = 32 * bx - 16, Y0 = 32 * by - 16;   // t-tile origin (can be -16)
    const bool edgeT = (bx == 0) | (by == 0) | (bx == 128) | (by == 128);
    const int tid = (int)threadIdx.x;

    // stage f on [X0-16, X0+48) x [Y0-16, Y0+48), skew-scatter (row = lx'+ly')
    for (int m = tid; m < 64 * 16; m += 256) {
        const int ly = m >> 4, lx4 = m & 15;
        const int lyp = ly - 16, lxp = 4 * lx4 - 16;
        float4 v;
        if (!edgeT) {
            v = *(const float4*)(src + (size_t)(Y0 + lyp) * N + (X0 + lxp));
        } else {
            const float* row = src + (size_t)mir(Y0 + lyp) * N;
            v = make_float4(row[mir(X0 + lxp)], row[mir(X0 + lxp + 1)],
                            row[mir(X0 + lxp + 2)], row[mir(X0 + lxp + 3)]);
        }
        const int r0   = lxp + lyp;    // skew row - 32
        const int col0 = lxp + 16;
#pragma unroll
        for (int e = 0; e < 4; ++e) {
            const int r = r0 + e;
            const float val = (e == 0) ? v.x : (e == 1) ? v.y : (e == 2) ? v.z : v.w;
            if (r >= 0 && r <= 62) S[r * SST + col0 + e] = val;
        }
    }
    __syncthreads();

    // conv: thread (d=tid>>2, h=tid&3), taps contiguous in skew row d
    const int d = tid >> 2, h = tid & 3;
    const int lo = max(0, d - 31), hi = min(31, d);
    const int L = (lo & ~3) + 8 * h;
    if ((d <= 62) && (L <= hi)) {
        float w[40];
#pragma unroll
        for (int j = 0; j < 10; ++j)
            *(float4*)&w[4 * j] = *(const float4*)&S[d * SST + L + 4 * j];
        float acc[8];
#pragma unroll
        for (int i = 0; i < 8; ++i) acc[i] = 0.f;
#pragma unroll
        for (int k = 0; k <= 32; ++k) {
            const float c = BIN32[k];
#pragma unroll
            for (int i = 0; i < 8; ++i) acc[i] = fmaf(c, w[i + k], acc[i]);
        }
#pragma unroll
        for (int i = 0; i < 8; ++i) {
            const int lx = L + i;
            if (lx >= lo && lx <= hi) S2[(d - lx) * OST + lx] = acc[i];
        }
    }
    __syncthreads();

    // writeback t
    {
        const int ly = tid >> 3, lx4 = tid & 7;
        const float4 v = *(const float4*)&S2[ly * OST + 4 * lx4];
        const int wcol = X0 + 4 * lx4 + 16;   // tx+16
        const int wrow = Y0 + ly + 16;        // ty+16
        if (wcol < N && wrow < N) {
            *(float4*)(tcore + (size_t)wrow * N + wcol) = v;
        } else {
            const int ty = Y0 + ly;
#pragma unroll
            for (int e = 0; e < 4; ++e) {
                const int tx = X0 + 4 * lx4 + e;
                const float val = (e == 0) ? v.x : (e == 1) ? v.y : (e == 2) ? v.z : v.w;
                tstrip[strip_off(tx, ty)] = val;
            }
        }
    }
}

// ---------------- P2: diagonal 33-tap pass + fused shade ----------------
// STRIPS=0: interior tiles (x0,y0 <= 4032), pure shifted-ws staging (always in-bounds).
// STRIPS=1: edge band (x0=4064 or y0=4064), per-element core/strip reads.
template <int STRIPS>
__global__ __launch_bounds__(256, 4) void p2_diag(const float* __restrict__ tcore,
                                                  const float* __restrict__ tstrip,
                                                  float* __restrict__ dst,
                                                  const float* __restrict__ xin,
                                                  const float* __restrict__ nrm) {
    __shared__ float S[63 * SST + SGUARD];
    __shared__ float S2[B * OST];
    int X0, Y0;
    if constexpr (STRIPS) {
        if (blockIdx.y == 0) { X0 = 4064; Y0 = 32 * (int)blockIdx.x; }
        else                 { X0 = 32 * (int)blockIdx.x; Y0 = 4064; }
    } else {
        X0 = 32 * (int)blockIdx.x; Y0 = 32 * (int)blockIdx.y;
    }
    const int tid = (int)threadIdx.x;

    // stage t on [X0-16, X0+48) x [Y0-16, Y0+48), skew-scatter (row = lx'-ly'+63)
    for (int m = tid; m < 64 * 16; m += 256) {
        const int ly = m >> 4, lx4 = m & 15;
        const int lyp = ly - 16, lxp = 4 * lx4 - 16;
        float4 v;
        if constexpr (!STRIPS) {
            v = *(const float4*)(tcore + (size_t)(Y0 + lyp + 16) * N + (X0 + lxp + 16));
        } else {
            const int ty = Y0 + lyp;
            float tmp[4];
#pragma unroll
            for (int e = 0; e < 4; ++e) {
                const int tx = X0 + lxp + e;
                tmp[e] = (tx < 4080 && ty < 4080)
                             ? tcore[(size_t)(ty + 16) * N + (tx + 16)]
                             : tstrip[strip_off(tx, ty)];
            }
            v = make_float4(tmp[0], tmp[1], tmp[2], tmp[3]);
        }
        const int r0   = lxp - lyp + 31;   // skew row - 32
        const int col0 = lxp + 16;
#pragma unroll
        for (int e = 0; e < 4; ++e) {
            const int r = r0 + e;
            const float val = (e == 0) ? v.x : (e == 1) ? v.y : (e == 2) ? v.z : v.w;
            if (r >= 0 && r <= 62) S[r * SST + col0 + e] = val;
        }
    }
    __syncthreads();

    const int d = tid >> 2, h = tid & 3;
    const int lo = max(0, d - 31), hi = min(31, d);
    const int L = (lo & ~3) + 8 * h;
    if ((d <= 62) && (L <= hi)) {
        float w[40];
#pragma unroll
        for (int j = 0; j < 10; ++j)
            *(float4*)&w[4 * j] = *(const float4*)&S[d * SST + L + 4 * j];
        float acc[8];
#pragma unroll
        for (int i = 0; i < 8; ++i) acc[i] = 0.f;
#pragma unroll
        for (int k = 0; k <= 32; ++k) {
            const float c = BIN32[k];
#pragma unroll
            for (int i = 0; i < 8; ++i) acc[i] = fmaf(c, w[i + k], acc[i]);
        }
#pragma unroll
        for (int i = 0; i < 8; ++i) {
            const int lx = L + i;
            if (lx >= lo && lx <= hi) S2[(lx - d + 31) * OST + lx] = acc[i];
        }
    }
    __syncthreads();

    // writeback + fused shade (always in-bounds)
    {
        const int ly = tid >> 3, lx4 = tid & 7;
        const float4 v = *(const float4*)&S2[ly * OST + 4 * lx4];
        const size_t base = (size_t)(Y0 + ly) * N + X0 + 4 * lx4;
        const float4 h4 = *(const float4*)(xin + base);
        const float4 n0 = *(const float4*)(nrm + base);
        const float4 n1 = *(const float4*)(nrm + (size_t)N * N + base);
        const float4 n2 = *(const float4*)(nrm + 2 * (size_t)N * N + base);
        *(float4*)(dst + base) = shade(v, h4, n0, n1, n2);
    }
}

extern "C" void kernel_launch(void* const* d_in, const int* in_sizes, int n_in,
                              void* d_out, int out_size, void* d_ws, size_t ws_size,
                              hipStream_t stream) {
    const float* x       = (const float*)d_in[0];
    const float* normals = (const float*)d_in[1];
    float* out = (float*)d_out;
    float* ws  = (float*)d_ws;

    dim3 block(256);

    // P1: t on [-16,4112)^2 (mirror-extended). Core -> ws (+16 shift), strips -> out R.
    p1_antidiag<<<dim3(129, 129), block, 0, stream>>>(x, ws, out);
    // P2 edge band (x0=4064 or y0=4064): strip-aware reads; writes only cols>=4064 / rows>=4064.
    p2_diag<1><<<dim3(128, 2), block, 0, stream>>>(ws, out, out, x, normals);
    // P2 interior (x0,y0 <= 4032): pure shifted-ws staging; overwrites R with final output.
    p2_diag<0><<<dim3(127, 127), block, 0, stream>>>(ws, out, out, x, normals);
}

// Round 15
// 147.265 us; speedup vs baseline: 2.5970x; 1.0565x over previous
//
#include <hip/hip_runtime.h>

#define N 4096
#define B 32
#define SST 66     // skew LDS row stride: lane-bank (12p+2q)%32 -> 16 banks, 4-way (was 8-way at 68)
#define OST 34     // out-tile stride: same de-phasing; readback via float2
#define SGUARD 64

// C(32,k) — binomial weights of (S+S^-1)^32; sum = 2^32 per pass.
__device__ constexpr float BIN32[33] = {
    1.f, 32.f, 496.f, 4960.f, 35960.f, 201376.f, 906192.f, 3365856.f,
    10518300.f, 28048800.f, 64512240.f, 129024480.f, 225792840.f,
    347373600.f, 471435600.f, 565722720.f, 601080390.f, 565722720.f,
    471435600.f, 347373600.f, 225792840.f, 129024480.f, 64512240.f,
    28048800.f, 10518300.f, 3365856.f, 906192.f, 201376.f, 35960.f,
    4960.f, 496.f, 32.f, 1.f};

// Half-sample mirror (replicate-pad iteration == free-space on this extension).
__device__ __forceinline__ int mir(int c) {
    c = (c < 0) ? (-1 - c) : c;
    return (c >= N) ? (2 * N - 1 - c) : c;
}

// bf16 RNE pack/unpack for the t intermediate.
__device__ __forceinline__ unsigned short f2bf(float x) {
    unsigned b = __float_as_uint(x);
    b += 0x7FFFu + ((b >> 16) & 1u);
    return (unsigned short)(b >> 16);
}
__device__ __forceinline__ float bf2f(unsigned short u) {
    return __uint_as_float(((unsigned)u) << 16);
}

// Extended-t strips (tx>=4080 or ty>=4080) live in d_out (f32) at rows 64..128, cols <4064
// (disjoint from every P2-edge write, overwritten by P2-interior afterwards).
__device__ __forceinline__ size_t strip_off(int tx, int ty) {
    long e = (tx >= 4080) ? ((long)(ty + 16) * 32 + (tx - 4080))            // R1: 32x4128
                          : (132096L + (long)(ty - 4080) * (long)N + (tx + 16)); // R2: 4096x32
    return (size_t)(64 + e / 4064) * N + (size_t)(e % 4064);
}

// Diffuse/AO shading for 4 pixels (rx carries 2^64 deferred scale).
__device__ __forceinline__ float4 shade(float4 v, float4 h, float4 n0, float4 n1, float4 n2) {
    const float SC = 0x1p-64f;
    const float L0 = 0.7053f, L1 = -0.7053f, L2 = 0.7053f;
    float4 o;
    {
        float ao = 1.0f - fminf(fmaxf((v.x * SC - h.x) * 4.0f, 0.0f), 1.0f);
        float d1 = fmaxf(n0.x * L0 + n1.x * L1 + n2.x * L2, 0.0f);
        o.x = (d1 * 0.3f + 0.7f) * ao;
    }
    {
        float ao = 1.0f - fminf(fmaxf((v.y * SC - h.y) * 4.0f, 0.0f), 1.0f);
        float d1 = fmaxf(n0.y * L0 + n1.y * L1 + n2.y * L2, 0.0f);
        o.y = (d1 * 0.3f + 0.7f) * ao;
    }
    {
        float ao = 1.0f - fminf(fmaxf((v.z * SC - h.z) * 4.0f, 0.0f), 1.0f);
        float d1 = fmaxf(n0.z * L0 + n1.z * L1 + n2.z * L2, 0.0f);
        o.z = (d1 * 0.3f + 0.7f) * ao;
    }
    {
        float ao = 1.0f - fminf(fmaxf((v.w * SC - h.w) * 4.0f, 0.0f), 1.0f);
        float d1 = fmaxf(n0.w * L0 + n1.w * L1 + n2.w * L2, 0.0f);
        o.w = (d1 * 0.3f + 0.7f) * ao;
    }
    return o;
}

// ---------------- P1: anti-diagonal 33-tap pass over extended grid ----------------
// Grid 129x129; tile covers t on [32bx-16, 32bx+16) x [32by-16, 32by+16).
// Mirror staging at edge tiles; core t -> ws as bf16 (+16 shift), strips -> d_out (f32).
__global__ __launch_bounds__(256, 4) void p1_antidiag(const float* __restrict__ src,
                                                      unsigned short* __restrict__ tcore,
                                                      float* __restrict__ tstrip) {
    __shared__ float S[63 * SST + SGUARD];
    __shared__ float S2[B * OST + 8];
    const int bx = blockIdx.x, by = blockIdx.y;
    const int X0 = 32 * bx - 16, Y0 = 32 * by - 16;   // t-tile origin (can be -16)
    const bool edgeT = (bx == 0) | (by == 0) | (bx == 128) | (by == 128);
    const int tid = (int)threadIdx.x;

    // stage f on [X0-16, X0+48) x [Y0-16, Y0+48), skew-scatter (row = lx'+ly')
    for (int m = tid; m < 64 * 16; m += 256) {
        const int ly = m >> 4, lx4 = m & 15;
        const int lyp = ly - 16, lxp = 4 * lx4 - 16;
        float4 v;
        if (!edgeT) {
            v = *(const float4*)(src + (size_t)(Y0 + lyp) * N + (X0 + lxp));
        } else {
            const float* row = src + (size_t)mir(Y0 + lyp) * N;
            v = make_float4(row[mir(X0 + lxp)], row[mir(X0 + lxp + 1)],
                            row[mir(X0 + lxp + 2)], row[mir(X0 + lxp + 3)]);
        }
        const int r0   = lxp + lyp;    // skew row - 32
        const int col0 = lxp + 16;
#pragma unroll
        for (int e = 0; e < 4; ++e) {
            const int r = r0 + e;
            const float val = (e == 0) ? v.x : (e == 1) ? v.y : (e == 2) ? v.z : v.w;
            if (r >= 0 && r <= 62) S[r * SST + col0 + e] = val;
        }
    }
    __syncthreads();

    // conv: thread (d=tid>>2, h=tid&3), taps contiguous in skew row d
    const int d = tid >> 2, h = tid & 3;
    const int lo = max(0, d - 31), hi = min(31, d);
    const int L = (lo & ~3) + 8 * h;
    if ((d <= 62) && (L <= hi)) {
        float w[40];
#pragma unroll
        for (int j = 0; j < 20; ++j)
            *(float2*)&w[2 * j] = *(const float2*)&S[d * SST + L + 2 * j];
        float acc[8];
#pragma unroll
        for (int i = 0; i < 8; ++i) acc[i] = 0.f;
#pragma unroll
        for (int k = 0; k <= 32; ++k) {
            const float c = BIN32[k];
#pragma unroll
            for (int i = 0; i < 8; ++i) acc[i] = fmaf(c, w[i + k], acc[i]);
        }
#pragma unroll
        for (int i = 0; i < 8; ++i) {
            const int lx = L + i;
            if (lx >= lo && lx <= hi) S2[(d - lx) * OST + lx] = acc[i];
        }
    }
    __syncthreads();

    // writeback t
    {
        const int ly = tid >> 3, lx4 = tid & 7;
        const float2 v01 = *(const float2*)&S2[ly * OST + 4 * lx4];
        const float2 v23 = *(const float2*)&S2[ly * OST + 4 * lx4 + 2];
        const int wcol = X0 + 4 * lx4 + 16;   // tx+16
        const int wrow = Y0 + ly + 16;        // ty+16
        if (wcol < N && wrow < N) {
            ushort4 u;
            u.x = f2bf(v01.x); u.y = f2bf(v01.y); u.z = f2bf(v23.x); u.w = f2bf(v23.y);
            *(ushort4*)(tcore + (size_t)wrow * N + wcol) = u;
        } else {
            const int ty = Y0 + ly;
            const float vv[4] = {v01.x, v01.y, v23.x, v23.y};
#pragma unroll
            for (int e = 0; e < 4; ++e) {
                const int tx = X0 + 4 * lx4 + e;
                tstrip[strip_off(tx, ty)] = vv[e];
            }
        }
    }
}

// ---------------- P2: diagonal 33-tap pass + fused shade ----------------
// STRIPS=0: interior tiles (x0,y0 <= 4032), pure shifted bf16-ws staging (in-bounds).
// STRIPS=1: edge band (x0=4064 or y0=4064), per-element core/strip reads.
template <int STRIPS>
__global__ __launch_bounds__(256, 4) void p2_diag(const unsigned short* __restrict__ tcore,
                                                  const float* __restrict__ tstrip,
                                                  float* __restrict__ dst,
                                                  const float* __restrict__ xin,
                                                  const float* __restrict__ nrm) {
    __shared__ float S[63 * SST + SGUARD];
    __shared__ float S2[B * OST + 8];
    int X0, Y0;
    if constexpr (STRIPS) {
        if (blockIdx.y == 0) { X0 = 4064; Y0 = 32 * (int)blockIdx.x; }
        else                 { X0 = 32 * (int)blockIdx.x; Y0 = 4064; }
    } else {
        X0 = 32 * (int)blockIdx.x; Y0 = 32 * (int)blockIdx.y;
    }
    const int tid = (int)threadIdx.x;

    // stage t on [X0-16, X0+48) x [Y0-16, Y0+48), skew-scatter (row = lx'-ly'+63)
    for (int m = tid; m < 64 * 16; m += 256) {
        const int ly = m >> 4, lx4 = m & 15;
        const int lyp = ly - 16, lxp = 4 * lx4 - 16;
        float4 v;
        if constexpr (!STRIPS) {
            const ushort4 u = *(const ushort4*)(tcore + (size_t)(Y0 + lyp + 16) * N + (X0 + lxp + 16));
            v = make_float4(bf2f(u.x), bf2f(u.y), bf2f(u.z), bf2f(u.w));
        } else {
            const int ty = Y0 + lyp;
            float tmp[4];
#pragma unroll
            for (int e = 0; e < 4; ++e) {
                const int tx = X0 + lxp + e;
                tmp[e] = (tx < 4080 && ty < 4080)
                             ? bf2f(tcore[(size_t)(ty + 16) * N + (tx + 16)])
                             : tstrip[strip_off(tx, ty)];
            }
            v = make_float4(tmp[0], tmp[1], tmp[2], tmp[3]);
        }
        const int r0   = lxp - lyp + 31;   // skew row - 32
        const int col0 = lxp + 16;
#pragma unroll
        for (int e = 0; e < 4; ++e) {
            const int r = r0 + e;
            const float val = (e == 0) ? v.x : (e == 1) ? v.y : (e == 2) ? v.z : v.w;
            if (r >= 0 && r <= 62) S[r * SST + col0 + e] = val;
        }
    }
    __syncthreads();

    const int d = tid >> 2, h = tid & 3;
    const int lo = max(0, d - 31), hi = min(31, d);
    const int L = (lo & ~3) + 8 * h;
    if ((d <= 62) && (L <= hi)) {
        float w[40];
#pragma unroll
        for (int j = 0; j < 20; ++j)
            *(float2*)&w[2 * j] = *(const float2*)&S[d * SST + L + 2 * j];
        float acc[8];
#pragma unroll
        for (int i = 0; i < 8; ++i) acc[i] = 0.f;
#pragma unroll
        for (int k = 0; k <= 32; ++k) {
            const float c = BIN32[k];
#pragma unroll
            for (int i = 0; i < 8; ++i) acc[i] = fmaf(c, w[i + k], acc[i]);
        }
#pragma unroll
        for (int i = 0; i < 8; ++i) {
            const int lx = L + i;
            if (lx >= lo && lx <= hi) S2[(lx - d + 31) * OST + lx] = acc[i];
        }
    }
    __syncthreads();

    // writeback + fused shade (always in-bounds)
    {
        const int ly = tid >> 3, lx4 = tid & 7;
        const float2 v01 = *(const float2*)&S2[ly * OST + 4 * lx4];
        const float2 v23 = *(const float2*)&S2[ly * OST + 4 * lx4 + 2];
        const float4 v = make_float4(v01.x, v01.y, v23.x, v23.y);
        const size_t base = (size_t)(Y0 + ly) * N + X0 + 4 * lx4;
        const float4 h4 = *(const float4*)(xin + base);
        const float4 n0 = *(const float4*)(nrm + base);
        const float4 n1 = *(const float4*)(nrm + (size_t)N * N + base);
        const float4 n2 = *(const float4*)(nrm + 2 * (size_t)N * N + base);
        *(float4*)(dst + base) = shade(v, h4, n0, n1, n2);
    }
}

extern "C" void kernel_launch(void* const* d_in, const int* in_sizes, int n_in,
                              void* d_out, int out_size, void* d_ws, size_t ws_size,
                              hipStream_t stream) {
    const float* x       = (const float*)d_in[0];
    const float* normals = (const float*)d_in[1];
    float* out = (float*)d_out;
    unsigned short* ws16 = (unsigned short*)d_ws;

    dim3 block(256);

    // P1: t on [-16,4112)^2 (mirror-extended). Core -> ws (bf16, +16 shift), strips -> out R (f32).
    p1_antidiag<<<dim3(129, 129), block, 0, stream>>>(x, ws16, out);
    // P2 edge band (x0=4064 or y0=4064): strip-aware reads; writes only cols>=4064 / rows>=4064.
    p2_diag<1><<<dim3(128, 2), block, 0, stream>>>(ws16, out, out, x, normals);
    // P2 interior (x0,y0 <= 4032): pure shifted bf16-ws staging; overwrites R with final output.
    p2_diag<0><<<dim3(127, 127), block, 0, stream>>>(ws16, out, out, x, normals);
}